// Round 7
// baseline (6197.775 us; speedup 1.0000x reference)
//
#include <hip/hip_runtime.h>
#include <hip/hip_fp16.h>
#include <stdint.h>

#define BB 128
#define SS 256
#define HH 512
#define QQ 360

// ---------------- Threefry-2x32 (JAX semantics) ----------------
struct TF2 { uint32_t a, b; };

__host__ __device__ constexpr uint32_t rotl32(uint32_t x, int d) {
  return (x << d) | (x >> (32 - d));
}

__host__ __device__ constexpr TF2 threefry(uint32_t k0, uint32_t k1,
                                           uint32_t x0, uint32_t x1) {
  uint32_t ks[3] = {k0, k1, k0 ^ k1 ^ 0x1BD11BDAu};
  x0 += ks[0]; x1 += ks[1];
  const int R0[4] = {13, 15, 26, 6};
  const int R1[4] = {17, 29, 16, 24};
  for (int g = 0; g < 5; ++g) {
    const int* r = (g & 1) ? R1 : R0;
    for (int i = 0; i < 4; ++i) { x0 += x1; x1 = rotl32(x1, r[i]); x1 ^= x0; }
    x0 += ks[(g + 1) % 3];
    x1 += ks[(g + 2) % 3] + (uint32_t)(g + 1);
  }
  return TF2{x0, x1};
}

struct KeyTab { uint32_t sk[256][2]; };
constexpr KeyTab make_keys() {
  KeyTab K{};
  uint32_t k0 = 0u, k1 = 1u;
  for (int t = 0; t < 256; ++t) {
    TF2 nk = threefry(k0, k1, 0u, 0u);
    TF2 sk = threefry(k0, k1, 0u, 1u);
    K.sk[t][0] = sk.a; K.sk[t][1] = sk.b;
    k0 = nk.a; k1 = nk.b;
  }
  return K;
}
__constant__ KeyTab c_keys = make_keys();

// ---------------- fast math helpers ----------------
__device__ __forceinline__ float frcp(float x) {
#if __has_builtin(__builtin_amdgcn_rcpf)
  return __builtin_amdgcn_rcpf(x);
#else
  return 1.0f / x;
#endif
}

#if __has_builtin(__builtin_amdgcn_exp2f)
  #define EXP2F(x) __builtin_amdgcn_exp2f(x)
  #define CC 2.8853900817779268f
#else
  #define EXP2F(x) __expf(x)
  #define CC 2.0f
#endif

#define ENC_QS 16.0f
#define ENC_INV (CC / ENC_QS)

__device__ __forceinline__ float fast_tanh(float x) {
  float e = __expf(2.0f * x);
  return 1.0f - 2.0f * frcp(e + 1.0f);
}

#if __has_builtin(__builtin_amdgcn_sdot4)
__device__ __forceinline__ int DOT4(int a, int b, int c) {
  return __builtin_amdgcn_sdot4(a, b, c, false);
}
#else
__device__ __forceinline__ int DOT4(int a, int b, int c) {
#pragma unroll
  for (int j = 0; j < 4; ++j)
    c += (int)(int8_t)(a >> (8 * j)) * (int)(int8_t)(b >> (8 * j));
  return c;
}
#endif

// ---------------- Phase A1: enc8[b][h][s] = int8( 16 * (inputs @ Wc + bc)^T ) ----------------
__global__ __launch_bounds__(256) void k_enc(const float* __restrict__ inputs,
                                             const float* __restrict__ Wc,
                                             const float* __restrict__ bc,
                                             int8_t* __restrict__ enc8) {
  const int ht = blockIdx.x;
  const int b  = blockIdx.y;
  const int tid = threadIdx.x;
  const int ts = tid & 63, th = tid >> 6;
  __shared__ float Xs[32 * 260];
  __shared__ float Ws[32 * 64];
  float acc[16][4];
#pragma unroll
  for (int i = 0; i < 16; ++i)
#pragma unroll
    for (int j = 0; j < 4; ++j) acc[i][j] = 0.f;

  const float* Arow = inputs + ((size_t)b * SS + tid) * HH;
  for (int kk = 0; kk < HH; kk += 32) {
    const float4* ip = (const float4*)(Arow + kk);
#pragma unroll
    for (int e = 0; e < 8; ++e) {
      float4 w = ip[e];
      Xs[(e * 4 + 0) * 260 + tid] = w.x;
      Xs[(e * 4 + 1) * 260 + tid] = w.y;
      Xs[(e * 4 + 2) * 260 + tid] = w.z;
      Xs[(e * 4 + 3) * 260 + tid] = w.w;
    }
    {
      int kw = tid >> 3, hw = (tid & 7) * 8;
      const float4* wp = (const float4*)(Wc + (size_t)(kk + kw) * HH + ht * 64 + hw);
      float4 w0 = wp[0], w1 = wp[1];
      float* d = Ws + kw * 64 + hw;
      ((float4*)d)[0] = w0; ((float4*)d)[1] = w1;
    }
    __syncthreads();
#pragma unroll 8
    for (int k = 0; k < 32; ++k) {
      float xr[4];
#pragma unroll
      for (int j = 0; j < 4; ++j) xr[j] = Xs[k * 260 + ts + 64 * j];
      const float4* wr4 = (const float4*)(Ws + k * 64 + th * 16);
#pragma unroll
      for (int i4 = 0; i4 < 4; ++i4) {
        float4 w = wr4[i4];
        float wv[4] = {w.x, w.y, w.z, w.w};
#pragma unroll
        for (int c = 0; c < 4; ++c)
#pragma unroll
          for (int j = 0; j < 4; ++j) acc[i4 * 4 + c][j] += wv[c] * xr[j];
      }
    }
    __syncthreads();
  }
#pragma unroll
  for (int i = 0; i < 16; ++i) {
    int h = ht * 64 + th * 16 + i;
    float bcv = bc[h];
    int8_t* orow = enc8 + (size_t)b * (HH * SS) + (size_t)h * SS + ts;
#pragma unroll
    for (int j = 0; j < 4; ++j) {
      float q = rintf(fminf(fmaxf((acc[i][j] + bcv) * ENC_QS, -127.f), 127.f));
      orow[64 * j] = (int8_t)(int)q;
    }
  }
}

// ---------------- Phase A2: G[b][j][k][q] = half( inputs[b,j,:] @ Wq[k] ) ----------------
__global__ __launch_bounds__(256) void k_G(const float* __restrict__ inputs,
                                           const float* __restrict__ Wq,
                                           __half* __restrict__ G) {
  const int qt = blockIdx.x;
  const int b  = blockIdx.y;
  const int k  = blockIdx.z;
  const int tid = threadIdx.x;
  const int ql = tid & 63, tj = tid >> 6;
  __shared__ float Xs[32 * 260];
  __shared__ float Ws[32 * 64];
  float acc[64];
#pragma unroll
  for (int j = 0; j < 64; ++j) acc[j] = 0.f;
  const int q = qt * 64 + ql;
  const float* Arow = inputs + ((size_t)b * SS + tid) * HH;
  const float* Wqk = Wq + (size_t)k * HH * QQ;
  for (int kk = 0; kk < HH; kk += 32) {
    const float4* ip = (const float4*)(Arow + kk);
#pragma unroll
    for (int e = 0; e < 8; ++e) {
      float4 w = ip[e];
      Xs[(e * 4 + 0) * 260 + tid] = w.x;
      Xs[(e * 4 + 1) * 260 + tid] = w.y;
      Xs[(e * 4 + 2) * 260 + tid] = w.z;
      Xs[(e * 4 + 3) * 260 + tid] = w.w;
    }
    {
      int hh = tid >> 3, qw = (tid & 7) * 8;
      const float* src = Wqk + (size_t)(kk + hh) * QQ;
      float* d = Ws + hh * 64 + qw;
#pragma unroll
      for (int e = 0; e < 8; ++e) {
        int qg = qt * 64 + qw + e;
        d[e] = (qg < QQ) ? src[qg] : 0.f;
      }
    }
    __syncthreads();
#pragma unroll 4
    for (int k2 = 0; k2 < 32; ++k2) {
      float wr = Ws[k2 * 64 + ql];
      const float4* xp = (const float4*)(Xs + k2 * 260 + tj * 64);
#pragma unroll
      for (int j4 = 0; j4 < 16; ++j4) {
        float4 x = xp[j4];
        acc[j4 * 4 + 0] += wr * x.x;
        acc[j4 * 4 + 1] += wr * x.y;
        acc[j4 * 4 + 2] += wr * x.z;
        acc[j4 * 4 + 3] += wr * x.w;
      }
    }
    __syncthreads();
  }
  if (q < QQ) {
#pragma unroll
    for (int j = 0; j < 64; ++j) {
      size_t jg = (size_t)b * SS + (tj * 64 + j);
      G[(jg * 3 + k) * QQ + q] = __float2half(acc[j]);
    }
  }
}

// ---------------- w_q fp32 -> int8 packed dwords: wq8d[h*96 + qd] ----------------
__global__ void k_wq8(const float* __restrict__ w_q, uint32_t* __restrict__ wq8d) {
  const int h = blockIdx.x;        // 512
  const int qd = threadIdx.x;      // 96
  uint32_t pack = 0;
#pragma unroll
  for (int j = 0; j < 4; ++j) {
    int q = qd * 4 + j;
    int v = 0;
    if (q < QQ) {
      float w = w_q[(size_t)q * HH + h] * 512.0f;
      v = (int)rintf(fminf(fmaxf(w, -127.f), 127.f));
    }
    pack |= ((uint32_t)(uint8_t)(int8_t)v) << (8 * j);
  }
  wq8d[(size_t)h * 96 + qd] = pack;
}

// ---------------- Gumbel precompute: gum[b][t][s] ----------------
__global__ __launch_bounds__(1024) void k_gum(float* __restrict__ gum) {
  const uint32_t idx = blockIdx.x * 1024 + threadIdx.x;
  const uint32_t b = idx >> 16;
  const uint32_t t = (idx >> 8) & 255;
  const uint32_t s = idx & 255;
  TF2 o = threefry(c_keys.sk[t][0], c_keys.sk[t][1], 0u, b * SS + s);
  float fb = __uint_as_float((o.b >> 9) | 0x3f800000u) - 1.0f;
  fb = fmaxf(fb, 1.0e-12f);
  gum[idx] = -__logf(-__logf(fb));
}

// ---------------- Main scan ----------------
// waves_per_eu(4,4): pin BOTH min and max occupancy to 4 waves/EU so the
// allocator actually spends the 128-VGPR budget (R5/R6: launch_bounds min
// alone left the heuristic at 8 waves/EU -> 64 VGPRs -> wq_r spilled to
// scratch, 6.4 GB/launch re-read = the whole step time).
__global__ __launch_bounds__(1024)
__attribute__((amdgpu_waves_per_eu(4, 4))) void k_scan(
    const uint32_t* __restrict__ wq8d, const float* __restrict__ v,
    const int8_t* __restrict__ enc8, const __half* __restrict__ G,
    const float* __restrict__ gum,
    float* __restrict__ out, double* __restrict__ lpb, double* __restrict__ entb) {
  const int b = blockIdx.x;
  const int tid = (int)threadIdx.x;
  const int lane = tid & 63;
  const int wid = tid >> 6;            // 16 waves
  // P2 geometry: lane = q_sub*8 + hq ; h = wid*32 + hq*4 + {0..3}
  const int q_sub = lane >> 3;
  const int hq = lane & 7;
  // P3 geometry
  const int hl = lane >> 5;
  const int sl = lane & 31;
  const int sbase = sl * 8;

  __shared__ float part[16][SS];
  __shared__ float2 evq[HH];           // .x = CC*eq[h], .y = -2*v[h]
  __shared__ float m_s[SS];
  __shared__ float mask_s[SS];
  __shared__ __align__(16) uint32_t q8_s[96];
  __shared__ float4 wred[4];
  __shared__ float Vtot_s;

  // ---- init ----
  if (tid < HH) evq[tid] = make_float2(0.f, -2.0f * v[tid]);
  if (tid < SS) mask_s[tid] = 0.f;
  if (tid < 96) q8_s[tid] = 0u;
  if (tid < 64) {
    float s = 0.f;
#pragma unroll
    for (int j = 0; j < 8; ++j) s += v[tid + 64 * j];
#pragma unroll
    for (int off = 32; off; off >>= 1) s += __shfl_xor(s, off);
    if (tid == 0) Vtot_s = s;
  }
  __syncthreads();
  const float Vtot = Vtot_s;

  // ---- step-invariant register state ----
  int wq_r[4][12];
#pragma unroll
  for (int hi = 0; hi < 4; ++hi) {
    const uint32_t* src = wq8d + (size_t)(wid * 32 + hq * 4 + hi) * 96 + q_sub * 12;
    int4 a = *(const int4*)(src);
    int4 bq = *(const int4*)(src + 4);
    int4 c = *(const int4*)(src + 8);
    wq_r[hi][0] = a.x;  wq_r[hi][1] = a.y;  wq_r[hi][2] = a.z;  wq_r[hi][3] = a.w;
    wq_r[hi][4] = bq.x; wq_r[hi][5] = bq.y; wq_r[hi][6] = bq.z; wq_r[hi][7] = bq.w;
    wq_r[hi][8] = c.x;  wq_r[hi][9] = c.y;  wq_r[hi][10] = c.z; wq_r[hi][11] = c.w;
  }
  uint2 enc_r[16];
  {
    const int8_t* encW = enc8 + (size_t)b * (HH * SS) + (size_t)(wid * 32 + hl) * SS + sbase;
#pragma unroll
    for (int i = 0; i < 16; ++i)
      enc_r[i] = *(const uint2*)(encW + (size_t)(2 * i) * SS);
  }

  const __half* Gb = G + (size_t)b * SS * 3 * QQ;
  const float* gumB = gum + (size_t)b * (SS * SS);

  double lp_acc = 0.0, ent_acc = 0.0;
  int first_idx = 0;
  int p1_r = -1, p2_r = -1;
  const bool pf = (tid < 90);

  for (int t = 0; t < SS; ++t) {
    // ---- prefetches (in flight through P2+P3) ----
    float gum_r = 0.f;
    if (tid < SS) gum_r = gumB[t * SS + tid];
    uint2 g0raw = make_uint2(0, 0), g1raw = make_uint2(0, 0);
    if (pf) {
      if (p1_r >= 0) g0raw = *(const uint2*)(Gb + ((size_t)p1_r * 3 + 0) * QQ + 4 * tid);
      if (p2_r >= 0) g1raw = *(const uint2*)(Gb + ((size_t)p2_r * 3 + 1) * QQ + 4 * tid);
    }

    // ---- P2: int8 dot4 GEMV, per-wave h-slice ----
    {
      const int qd0 = q_sub * 12;
      int4 qa = *(const int4*)&q8_s[qd0];
      int4 qb = *(const int4*)&q8_s[qd0 + 4];
      int4 qc = *(const int4*)&q8_s[qd0 + 8];
      int qv[12] = {qa.x, qa.y, qa.z, qa.w, qb.x, qb.y, qb.z, qb.w,
                    qc.x, qc.y, qc.z, qc.w};
      int acc0 = 0, acc1 = 0, acc2 = 0, acc3 = 0;
#pragma unroll
      for (int i = 0; i < 12; ++i) {
        acc0 = DOT4(qv[i], wq_r[0][i], acc0);
        acc1 = DOT4(qv[i], wq_r[1][i], acc1);
        acc2 = DOT4(qv[i], wq_r[2][i], acc2);
        acc3 = DOT4(qv[i], wq_r[3][i], acc3);
      }
#pragma unroll
      for (int off = 8; off <= 32; off <<= 1) {
        acc0 += __shfl_xor(acc0, off);
        acc1 += __shfl_xor(acc1, off);
        acc2 += __shfl_xor(acc2, off);
        acc3 += __shfl_xor(acc3, off);
      }
      if (lane < 8) {    // q_sub == 0, hq == lane
        int h0 = (wid << 5) + (lane << 2);
        // eq = dot / (16*512); store CC*eq
        evq[h0 + 0].x = (float)acc0 * (CC / 8192.0f);
        evq[h0 + 1].x = (float)acc1 * (CC / 8192.0f);
        evq[h0 + 2].x = (float)acc2 * (CC / 8192.0f);
        evq[h0 + 3].x = (float)acc3 * (CC / 8192.0f);
      }
      // in-wave visibility: compiler inserts lgkmcnt before evq reads below
    }

    // ---- P3: exp2-based tanh scores from register-resident enc ----
    {
      float acc[8];
#pragma unroll
      for (int j = 0; j < 8; ++j) acc[j] = 0.f;
#pragma unroll
      for (int i = 0; i < 16; ++i) {
        float2 ev = evq[(wid << 5) + 2 * i + hl];
        const float eqC = ev.x, mv = ev.y;
        const uint32_t w0 = enc_r[i].x, w1 = enc_r[i].y;
#pragma unroll
        for (int k = 0; k < 4; ++k) {
          {
            float f = (float)(int)(int8_t)(w0 >> (8 * k));
            float e = EXP2F(fmaf(f, ENC_INV, eqC));
            acc[k] = fmaf(mv, frcp(e + 1.0f), acc[k]);
          }
          {
            float f = (float)(int)(int8_t)(w1 >> (8 * k));
            float e = EXP2F(fmaf(f, ENC_INV, eqC));
            acc[4 + k] = fmaf(mv, frcp(e + 1.0f), acc[4 + k]);
          }
        }
      }
#pragma unroll
      for (int j = 0; j < 8; ++j) acc[j] += __shfl_xor(acc[j], 32);
      if (hl == 0) {
        *(float4*)&part[wid][sbase]     = make_float4(acc[0], acc[1], acc[2], acc[3]);
        *(float4*)&part[wid][sbase + 4] = make_float4(acc[4], acc[5], acc[6], acc[7]);
      }
    }
    __syncthreads();   // b1: part ready

    // ---- P4: 4 waves; logits, gumbel, argmax, sums ----
    if (tid < SS) {
      const int s = tid;
      float sc = Vtot;
#pragma unroll
      for (int r = 0; r < 16; ++r) sc += part[r][s];
      float logit = 10.0f * fast_tanh(sc);
      float m = (mask_s[s] != 0.f) ? -1.0e8f : logit;
      m_s[s] = m;
      float z = m + gum_r;
      float e = __expf(m);
      float em = e * m;
      int si = s;
#pragma unroll
      for (int off = 32; off; off >>= 1) {
        float zo = __shfl_xor(z, off);
        int io = __shfl_xor(si, off);
        if (zo > z || (zo == z && io < si)) { z = zo; si = io; }
        e += __shfl_xor(e, off);
        em += __shfl_xor(em, off);
      }
      if (lane == 0) wred[wid] = make_float4(z, __int_as_float(si), e, em);
    }
    __syncthreads();   // b2: wred, m_s ready

    // ---- finalize (all threads redundantly) ----
    {
      float4 r0 = wred[0], r1 = wred[1], r2 = wred[2], r3 = wred[3];
      float z = r0.x; int si = __float_as_int(r0.y);
      int i1 = __float_as_int(r1.y);
      if (r1.x > z || (r1.x == z && i1 < si)) { z = r1.x; si = i1; }
      int i2 = __float_as_int(r2.y);
      if (r2.x > z || (r2.x == z && i2 < si)) { z = r2.x; si = i2; }
      int i3 = __float_as_int(r3.y);
      if (r3.x > z || (r3.x == z && i3 < si)) { z = r3.x; si = i3; }
      const int idx = si;

      if (pf) {   // next q = relu(g0 + g1 + G2[idx]), packed to int8 (scale 16)
        uint2 g2 = *(const uint2*)(Gb + ((size_t)idx * 3 + 2) * QQ + 4 * tid);
        float2 f0a = __half22float2(*(const __half2*)&g0raw.x);
        float2 f0b = __half22float2(*(const __half2*)&g0raw.y);
        float2 f1a = __half22float2(*(const __half2*)&g1raw.x);
        float2 f1b = __half22float2(*(const __half2*)&g1raw.y);
        float2 f2a = __half22float2(*(const __half2*)&g2.x);
        float2 f2b = __half22float2(*(const __half2*)&g2.y);
        float q0 = fmaxf(f0a.x + f1a.x + f2a.x, 0.f);
        float q1 = fmaxf(f0a.y + f1a.y + f2a.y, 0.f);
        float q2 = fmaxf(f0b.x + f1b.x + f2b.x, 0.f);
        float q3 = fmaxf(f0b.y + f1b.y + f2b.y, 0.f);
        uint32_t u0 = min((uint32_t)(q0 * 16.0f + 0.5f), 127u);
        uint32_t u1 = min((uint32_t)(q1 * 16.0f + 0.5f), 127u);
        uint32_t u2 = min((uint32_t)(q2 * 16.0f + 0.5f), 127u);
        uint32_t u3 = min((uint32_t)(q3 * 16.0f + 0.5f), 127u);
        q8_s[tid] = u0 | (u1 << 8) | (u2 << 16) | (u3 << 24);
      }
      if (tid == 0) {
        float se = r0.z + r1.z + r2.z + r3.z;
        float sem = r0.w + r1.w + r2.w + r3.w;
        float lse = __logf(se);
        float mi = m_s[idx];
        lp_acc += (double)(mi - lse);
        ent_acc += (double)(lse - sem / se);
        out[b * 257 + t] = (float)idx;
        mask_s[idx] = 1.0f;
      }
      if (t == 0) first_idx = idx;
      p1_r = p2_r; p2_r = idx;
    }
    __syncthreads();   // b3: q8_s, mask updated
  }

  if (tid == 0) {
    out[b * 257 + 256] = (float)first_idx;
    lpb[b] = lp_acc;
    entb[b] = ent_acc;
  }
}

// ---------------- Final deterministic reduction ----------------
__global__ void k_final(const double* __restrict__ lpb,
                        const double* __restrict__ entb, float* __restrict__ out) {
  if (threadIdx.x == 0) {
    double a = 0.0, c = 0.0;
    for (int i = 0; i < BB; ++i) { a += lpb[i]; c += entb[i]; }
    out[BB * 257 + 0] = (float)a;
    out[BB * 257 + 1] = (float)c;
  }
}

extern "C" void kernel_launch(void* const* d_in, const int* in_sizes, int n_in,
                              void* d_out, int out_size, void* d_ws, size_t ws_size,
                              hipStream_t stream) {
  const float* inputs = (const float*)d_in[0];
  const float* Wc  = (const float*)d_in[1];
  const float* bc  = (const float*)d_in[2];
  const float* Wq  = (const float*)d_in[3];
  const float* w_q = (const float*)d_in[4];
  const float* v   = (const float*)d_in[5];
  float* out = (float*)d_out;

  char* ws = (char*)d_ws;
  const size_t encBytes = (size_t)BB * HH * SS;            // 16.8 MB int8
  const size_t gBytes   = (size_t)3 * BB * SS * QQ * 2;    // 70.8 MB fp16
  const size_t wqBytes  = (size_t)HH * 96 * 4;             // 196 KB int8-packed
  const size_t gumBytes = (size_t)BB * SS * SS * 4;        // 33.6 MB fp32
  int8_t*   enc8 = (int8_t*)ws;
  __half*   G    = (__half*)(ws + encBytes);
  uint32_t* wq8d = (uint32_t*)(ws + encBytes + gBytes);
  float*    gumP = (float*)(ws + encBytes + gBytes + wqBytes);
  size_t goff = (encBytes + gBytes + wqBytes + gumBytes + 1023) & ~(size_t)1023;
  double* lpb = (double*)(ws + goff);
  double* entb = lpb + BB;

  dim3 gA1(8, BB);
  k_enc<<<gA1, 256, 0, stream>>>(inputs, Wc, bc, enc8);
  dim3 gA2(6, BB, 3);
  k_G<<<gA2, 256, 0, stream>>>(inputs, Wq, G);
  k_wq8<<<HH, 96, 0, stream>>>(w_q, wq8d);
  k_gum<<<(BB * SS * SS) / 1024, 1024, 0, stream>>>(gumP);
  k_scan<<<BB, 1024, 0, stream>>>(wq8d, v, enc8, G, gumP, out, lpb, entb);
  k_final<<<1, 64, 0, stream>>>(lpb, entb, out);
}

// Round 8
// 6128.074 us; speedup vs baseline: 1.0114x; 1.0114x over previous
//
#include <hip/hip_runtime.h>
#include <hip/hip_fp16.h>
#include <stdint.h>

#define BB 128
#define SS 256
#define HH 512
#define QQ 360

// ---------------- Threefry-2x32 (JAX semantics) ----------------
struct TF2 { uint32_t a, b; };

__host__ __device__ constexpr uint32_t rotl32(uint32_t x, int d) {
  return (x << d) | (x >> (32 - d));
}

__host__ __device__ constexpr TF2 threefry(uint32_t k0, uint32_t k1,
                                           uint32_t x0, uint32_t x1) {
  uint32_t ks[3] = {k0, k1, k0 ^ k1 ^ 0x1BD11BDAu};
  x0 += ks[0]; x1 += ks[1];
  const int R0[4] = {13, 15, 26, 6};
  const int R1[4] = {17, 29, 16, 24};
  for (int g = 0; g < 5; ++g) {
    const int* r = (g & 1) ? R1 : R0;
    for (int i = 0; i < 4; ++i) { x0 += x1; x1 = rotl32(x1, r[i]); x1 ^= x0; }
    x0 += ks[(g + 1) % 3];
    x1 += ks[(g + 2) % 3] + (uint32_t)(g + 1);
  }
  return TF2{x0, x1};
}

struct KeyTab { uint32_t sk[256][2]; };
constexpr KeyTab make_keys() {
  KeyTab K{};
  uint32_t k0 = 0u, k1 = 1u;
  for (int t = 0; t < 256; ++t) {
    TF2 nk = threefry(k0, k1, 0u, 0u);
    TF2 sk = threefry(k0, k1, 0u, 1u);
    K.sk[t][0] = sk.a; K.sk[t][1] = sk.b;
    k0 = nk.a; k1 = nk.b;
  }
  return K;
}
__constant__ KeyTab c_keys = make_keys();

// ---------------- fast math helpers ----------------
__device__ __forceinline__ float frcp(float x) {
#if __has_builtin(__builtin_amdgcn_rcpf)
  return __builtin_amdgcn_rcpf(x);
#else
  return 1.0f / x;
#endif
}

#if __has_builtin(__builtin_amdgcn_exp2f)
  #define EXP2F(x) __builtin_amdgcn_exp2f(x)
  #define CC 2.8853900817779268f
#else
  #define EXP2F(x) __expf(x)
  #define CC 2.0f
#endif

#define ENC_QS 16.0f
#define ENC_INV (CC / ENC_QS)

__device__ __forceinline__ float fast_tanh(float x) {
  float e = __expf(2.0f * x);
  return 1.0f - 2.0f * frcp(e + 1.0f);
}

#if __has_builtin(__builtin_amdgcn_sdot4)
__device__ __forceinline__ int DOT4(int a, int b, int c) {
  return __builtin_amdgcn_sdot4(a, b, c, false);
}
#else
__device__ __forceinline__ int DOT4(int a, int b, int c) {
#pragma unroll
  for (int j = 0; j < 4; ++j)
    c += (int)(int8_t)(a >> (8 * j)) * (int)(int8_t)(b >> (8 * j));
  return c;
}
#endif

// ---------------- Phase A1: enc8[b][h][s] = int8( 16 * (inputs @ Wc + bc)^T ) ----------------
__global__ __launch_bounds__(256) void k_enc(const float* __restrict__ inputs,
                                             const float* __restrict__ Wc,
                                             const float* __restrict__ bc,
                                             int8_t* __restrict__ enc8) {
  const int ht = blockIdx.x;
  const int b  = blockIdx.y;
  const int tid = threadIdx.x;
  const int ts = tid & 63, th = tid >> 6;
  __shared__ float Xs[32 * 260];
  __shared__ float Ws[32 * 64];
  float acc[16][4];
#pragma unroll
  for (int i = 0; i < 16; ++i)
#pragma unroll
    for (int j = 0; j < 4; ++j) acc[i][j] = 0.f;

  const float* Arow = inputs + ((size_t)b * SS + tid) * HH;
  for (int kk = 0; kk < HH; kk += 32) {
    const float4* ip = (const float4*)(Arow + kk);
#pragma unroll
    for (int e = 0; e < 8; ++e) {
      float4 w = ip[e];
      Xs[(e * 4 + 0) * 260 + tid] = w.x;
      Xs[(e * 4 + 1) * 260 + tid] = w.y;
      Xs[(e * 4 + 2) * 260 + tid] = w.z;
      Xs[(e * 4 + 3) * 260 + tid] = w.w;
    }
    {
      int kw = tid >> 3, hw = (tid & 7) * 8;
      const float4* wp = (const float4*)(Wc + (size_t)(kk + kw) * HH + ht * 64 + hw);
      float4 w0 = wp[0], w1 = wp[1];
      float* d = Ws + kw * 64 + hw;
      ((float4*)d)[0] = w0; ((float4*)d)[1] = w1;
    }
    __syncthreads();
#pragma unroll 8
    for (int k = 0; k < 32; ++k) {
      float xr[4];
#pragma unroll
      for (int j = 0; j < 4; ++j) xr[j] = Xs[k * 260 + ts + 64 * j];
      const float4* wr4 = (const float4*)(Ws + k * 64 + th * 16);
#pragma unroll
      for (int i4 = 0; i4 < 4; ++i4) {
        float4 w = wr4[i4];
        float wv[4] = {w.x, w.y, w.z, w.w};
#pragma unroll
        for (int c = 0; c < 4; ++c)
#pragma unroll
          for (int j = 0; j < 4; ++j) acc[i4 * 4 + c][j] += wv[c] * xr[j];
      }
    }
    __syncthreads();
  }
#pragma unroll
  for (int i = 0; i < 16; ++i) {
    int h = ht * 64 + th * 16 + i;
    float bcv = bc[h];
    int8_t* orow = enc8 + (size_t)b * (HH * SS) + (size_t)h * SS + ts;
#pragma unroll
    for (int j = 0; j < 4; ++j) {
      float q = rintf(fminf(fmaxf((acc[i][j] + bcv) * ENC_QS, -127.f), 127.f));
      orow[64 * j] = (int8_t)(int)q;
    }
  }
}

// ---------------- Phase A2: G[b][j][k][q] = half( inputs[b,j,:] @ Wq[k] ) ----------------
__global__ __launch_bounds__(256) void k_G(const float* __restrict__ inputs,
                                           const float* __restrict__ Wq,
                                           __half* __restrict__ G) {
  const int qt = blockIdx.x;
  const int b  = blockIdx.y;
  const int k  = blockIdx.z;
  const int tid = threadIdx.x;
  const int ql = tid & 63, tj = tid >> 6;
  __shared__ float Xs[32 * 260];
  __shared__ float Ws[32 * 64];
  float acc[64];
#pragma unroll
  for (int j = 0; j < 64; ++j) acc[j] = 0.f;
  const int q = qt * 64 + ql;
  const float* Arow = inputs + ((size_t)b * SS + tid) * HH;
  const float* Wqk = Wq + (size_t)k * HH * QQ;
  for (int kk = 0; kk < HH; kk += 32) {
    const float4* ip = (const float4*)(Arow + kk);
#pragma unroll
    for (int e = 0; e < 8; ++e) {
      float4 w = ip[e];
      Xs[(e * 4 + 0) * 260 + tid] = w.x;
      Xs[(e * 4 + 1) * 260 + tid] = w.y;
      Xs[(e * 4 + 2) * 260 + tid] = w.z;
      Xs[(e * 4 + 3) * 260 + tid] = w.w;
    }
    {
      int hh = tid >> 3, qw = (tid & 7) * 8;
      const float* src = Wqk + (size_t)(kk + hh) * QQ;
      float* d = Ws + hh * 64 + qw;
#pragma unroll
      for (int e = 0; e < 8; ++e) {
        int qg = qt * 64 + qw + e;
        d[e] = (qg < QQ) ? src[qg] : 0.f;
      }
    }
    __syncthreads();
#pragma unroll 4
    for (int k2 = 0; k2 < 32; ++k2) {
      float wr = Ws[k2 * 64 + ql];
      const float4* xp = (const float4*)(Xs + k2 * 260 + tj * 64);
#pragma unroll
      for (int j4 = 0; j4 < 16; ++j4) {
        float4 x = xp[j4];
        acc[j4 * 4 + 0] += wr * x.x;
        acc[j4 * 4 + 1] += wr * x.y;
        acc[j4 * 4 + 2] += wr * x.z;
        acc[j4 * 4 + 3] += wr * x.w;
      }
    }
    __syncthreads();
  }
  if (q < QQ) {
#pragma unroll
    for (int j = 0; j < 64; ++j) {
      size_t jg = (size_t)b * SS + (tj * 64 + j);
      G[(jg * 3 + k) * QQ + q] = __float2half(acc[j]);
    }
  }
}

// ---------------- w_q fp32 -> int8 packed dwords: wq8d[h*96 + qd] ----------------
__global__ void k_wq8(const float* __restrict__ w_q, uint32_t* __restrict__ wq8d) {
  const int h = blockIdx.x;        // 512
  const int qd = threadIdx.x;      // 96
  uint32_t pack = 0;
#pragma unroll
  for (int j = 0; j < 4; ++j) {
    int q = qd * 4 + j;
    int v = 0;
    if (q < QQ) {
      float w = w_q[(size_t)q * HH + h] * 512.0f;
      v = (int)rintf(fminf(fmaxf(w, -127.f), 127.f));
    }
    pack |= ((uint32_t)(uint8_t)(int8_t)v) << (8 * j);
  }
  wq8d[(size_t)h * 96 + qd] = pack;
}

// ---------------- Gumbel precompute: gum[b][t][s] ----------------
__global__ __launch_bounds__(1024) void k_gum(float* __restrict__ gum) {
  const uint32_t idx = blockIdx.x * 1024 + threadIdx.x;
  const uint32_t b = idx >> 16;
  const uint32_t t = (idx >> 8) & 255;
  const uint32_t s = idx & 255;
  TF2 o = threefry(c_keys.sk[t][0], c_keys.sk[t][1], 0u, b * SS + s);
  float fb = __uint_as_float((o.b >> 9) | 0x3f800000u) - 1.0f;
  fb = fmaxf(fb, 1.0e-12f);
  gum[idx] = -__logf(-__logf(fb));
}

// ---------------- Main scan ----------------
// P2 streams int8 w_q from L2 every step (196 KB/CU/step; one shared copy
// per XCD L2 -> resident). No large per-thread arrays: R5-R7 proved the
// allocator spills >32-dword arrays to scratch (6.4 GB/launch HBM re-read).
__global__ __launch_bounds__(1024) void k_scan(
    const uint32_t* __restrict__ wq8d, const float* __restrict__ v,
    const int8_t* __restrict__ enc8, const __half* __restrict__ G,
    const float* __restrict__ gum,
    float* __restrict__ out, double* __restrict__ lpb, double* __restrict__ entb) {
  const int b = blockIdx.x;
  const int tid = (int)threadIdx.x;
  const int lane = tid & 63;
  const int wid = tid >> 6;            // 16 waves
  // P2 geometry: lane = half*32 + hh; h = wid*32 + hh, q-half = half*180
  const int hh = lane & 31;
  const int half = lane >> 5;
  // P3 geometry
  const int hl = lane >> 5;
  const int sl = lane & 31;
  const int sbase = sl * 8;

  __shared__ float part[16][SS];
  __shared__ float2 evq[HH];           // .x = CC*eq[h], .y = -2*v[h]
  __shared__ float m_s[SS];
  __shared__ float mask_s[SS];
  __shared__ __align__(16) uint32_t q8_s[96];
  __shared__ float4 wred[4];
  __shared__ float Vtot_s;

  // ---- init ----
  if (tid < HH) evq[tid] = make_float2(0.f, -2.0f * v[tid]);
  if (tid < SS) mask_s[tid] = 0.f;
  if (tid < 96) q8_s[tid] = 0u;
  if (tid < 64) {
    float s = 0.f;
#pragma unroll
    for (int j = 0; j < 8; ++j) s += v[tid + 64 * j];
#pragma unroll
    for (int off = 32; off; off >>= 1) s += __shfl_xor(s, off);
    if (tid == 0) Vtot_s = s;
  }
  __syncthreads();
  const float Vtot = Vtot_s;

  // ---- enc slice in registers (32 VGPRs; proven no-spill at this size, R4) ----
  uint2 enc_r[16];
  {
    const int8_t* encW = enc8 + (size_t)b * (HH * SS) + (size_t)(wid * 32 + hl) * SS + sbase;
#pragma unroll
    for (int i = 0; i < 16; ++i)
      enc_r[i] = *(const uint2*)(encW + (size_t)(2 * i) * SS);
  }

  const uint32_t* wrow = wq8d + (size_t)(wid * 32 + hh) * 96 + half * 48;
  const __half* Gb = G + (size_t)b * SS * 3 * QQ;
  const float* gumB = gum + (size_t)b * (SS * SS);

  double lp_acc = 0.0, ent_acc = 0.0;
  int first_idx = 0;
  int p1_r = -1, p2_r = -1;
  const bool pf = (tid < 90);

  for (int t = 0; t < SS; ++t) {
    // ---- prefetches (in flight through P2+P3) ----
    float gum_r = 0.f;
    if (tid < SS) gum_r = gumB[t * SS + tid];
    uint2 g0raw = make_uint2(0, 0), g1raw = make_uint2(0, 0);
    if (pf) {
      if (p1_r >= 0) g0raw = *(const uint2*)(Gb + ((size_t)p1_r * 3 + 0) * QQ + 4 * tid);
      if (p2_r >= 0) g1raw = *(const uint2*)(Gb + ((size_t)p2_r * 3 + 1) * QQ + 4 * tid);
    }

    // ---- P2: int8 dot4 GEMV; w streamed from L2, q broadcast from LDS ----
    {
      const uint32_t* qrow = q8_s + half * 48;
      int accA = 0, accB = 0;
#pragma unroll
      for (int i = 0; i < 6; ++i) {
        int4 w0 = *(const int4*)(wrow + 8 * i);
        int4 w1 = *(const int4*)(wrow + 8 * i + 4);
        int4 qv0 = *(const int4*)(qrow + 8 * i);
        int4 qv1 = *(const int4*)(qrow + 8 * i + 4);
        accA = DOT4(w0.x, qv0.x, accA);
        accA = DOT4(w0.y, qv0.y, accA);
        accA = DOT4(w0.z, qv0.z, accA);
        accA = DOT4(w0.w, qv0.w, accA);
        accB = DOT4(w1.x, qv1.x, accB);
        accB = DOT4(w1.y, qv1.y, accB);
        accB = DOT4(w1.z, qv1.z, accB);
        accB = DOT4(w1.w, qv1.w, accB);
      }
      int acc = accA + accB;
      acc += __shfl_xor(acc, 32);      // combine the two q-halves (same h)
      if (half == 0)
        evq[(wid << 5) + hh].x = (float)acc * (CC / 8192.0f);
      // in-wave write->read ordering; compiler inserts lgkmcnt before P3 reads
    }

    // ---- P3: exp2-based tanh scores from register-resident enc ----
    {
      float acc[8];
#pragma unroll
      for (int j = 0; j < 8; ++j) acc[j] = 0.f;
#pragma unroll
      for (int i = 0; i < 16; ++i) {
        float2 ev = evq[(wid << 5) + 2 * i + hl];
        const float eqC = ev.x, mv = ev.y;
        const uint32_t w0 = enc_r[i].x, w1 = enc_r[i].y;
#pragma unroll
        for (int k = 0; k < 4; ++k) {
          {
            float f = (float)(int)(int8_t)(w0 >> (8 * k));
            float e = EXP2F(fmaf(f, ENC_INV, eqC));
            acc[k] = fmaf(mv, frcp(e + 1.0f), acc[k]);
          }
          {
            float f = (float)(int)(int8_t)(w1 >> (8 * k));
            float e = EXP2F(fmaf(f, ENC_INV, eqC));
            acc[4 + k] = fmaf(mv, frcp(e + 1.0f), acc[4 + k]);
          }
        }
      }
#pragma unroll
      for (int j = 0; j < 8; ++j) acc[j] += __shfl_xor(acc[j], 32);
      if (hl == 0) {
        *(float4*)&part[wid][sbase]     = make_float4(acc[0], acc[1], acc[2], acc[3]);
        *(float4*)&part[wid][sbase + 4] = make_float4(acc[4], acc[5], acc[6], acc[7]);
      }
    }
    __syncthreads();   // b1: part ready

    // ---- P4: 4 waves; logits, gumbel, argmax, sums ----
    if (tid < SS) {
      const int s = tid;
      float sc = Vtot;
#pragma unroll
      for (int r = 0; r < 16; ++r) sc += part[r][s];
      float logit = 10.0f * fast_tanh(sc);
      float m = (mask_s[s] != 0.f) ? -1.0e8f : logit;
      m_s[s] = m;
      float z = m + gum_r;
      float e = __expf(m);
      float em = e * m;
      int si = s;
#pragma unroll
      for (int off = 32; off; off >>= 1) {
        float zo = __shfl_xor(z, off);
        int io = __shfl_xor(si, off);
        if (zo > z || (zo == z && io < si)) { z = zo; si = io; }
        e += __shfl_xor(e, off);
        em += __shfl_xor(em, off);
      }
      if (lane == 0) wred[wid] = make_float4(z, __int_as_float(si), e, em);
    }
    __syncthreads();   // b2: wred, m_s ready

    // ---- finalize (all threads redundantly) ----
    {
      float4 r0 = wred[0], r1 = wred[1], r2 = wred[2], r3 = wred[3];
      float z = r0.x; int si = __float_as_int(r0.y);
      int i1 = __float_as_int(r1.y);
      if (r1.x > z || (r1.x == z && i1 < si)) { z = r1.x; si = i1; }
      int i2 = __float_as_int(r2.y);
      if (r2.x > z || (r2.x == z && i2 < si)) { z = r2.x; si = i2; }
      int i3 = __float_as_int(r3.y);
      if (r3.x > z || (r3.x == z && i3 < si)) { z = r3.x; si = i3; }
      const int idx = si;

      if (pf) {   // next q = relu(g0 + g1 + G2[idx]), packed to int8 (scale 16)
        uint2 g2 = *(const uint2*)(Gb + ((size_t)idx * 3 + 2) * QQ + 4 * tid);
        float2 f0a = __half22float2(*(const __half2*)&g0raw.x);
        float2 f0b = __half22float2(*(const __half2*)&g0raw.y);
        float2 f1a = __half22float2(*(const __half2*)&g1raw.x);
        float2 f1b = __half22float2(*(const __half2*)&g1raw.y);
        float2 f2a = __half22float2(*(const __half2*)&g2.x);
        float2 f2b = __half22float2(*(const __half2*)&g2.y);
        float q0 = fmaxf(f0a.x + f1a.x + f2a.x, 0.f);
        float q1 = fmaxf(f0a.y + f1a.y + f2a.y, 0.f);
        float q2 = fmaxf(f0b.x + f1b.x + f2b.x, 0.f);
        float q3 = fmaxf(f0b.y + f1b.y + f2b.y, 0.f);
        uint32_t u0 = min((uint32_t)(q0 * 16.0f + 0.5f), 127u);
        uint32_t u1 = min((uint32_t)(q1 * 16.0f + 0.5f), 127u);
        uint32_t u2 = min((uint32_t)(q2 * 16.0f + 0.5f), 127u);
        uint32_t u3 = min((uint32_t)(q3 * 16.0f + 0.5f), 127u);
        q8_s[tid] = u0 | (u1 << 8) | (u2 << 16) | (u3 << 24);
      }
      if (tid == 0) {
        float se = r0.z + r1.z + r2.z + r3.z;
        float sem = r0.w + r1.w + r2.w + r3.w;
        float lse = __logf(se);
        float mi = m_s[idx];
        lp_acc += (double)(mi - lse);
        ent_acc += (double)(lse - sem / se);
        out[b * 257 + t] = (float)idx;
        mask_s[idx] = 1.0f;
      }
      if (t == 0) first_idx = idx;
      p1_r = p2_r; p2_r = idx;
    }
    __syncthreads();   // b3: q8_s, mask updated
  }

  if (tid == 0) {
    out[b * 257 + 256] = (float)first_idx;
    lpb[b] = lp_acc;
    entb[b] = ent_acc;
  }
}

// ---------------- Final deterministic reduction ----------------
__global__ void k_final(const double* __restrict__ lpb,
                        const double* __restrict__ entb, float* __restrict__ out) {
  if (threadIdx.x == 0) {
    double a = 0.0, c = 0.0;
    for (int i = 0; i < BB; ++i) { a += lpb[i]; c += entb[i]; }
    out[BB * 257 + 0] = (float)a;
    out[BB * 257 + 1] = (float)c;
  }
}

extern "C" void kernel_launch(void* const* d_in, const int* in_sizes, int n_in,
                              void* d_out, int out_size, void* d_ws, size_t ws_size,
                              hipStream_t stream) {
  const float* inputs = (const float*)d_in[0];
  const float* Wc  = (const float*)d_in[1];
  const float* bc  = (const float*)d_in[2];
  const float* Wq  = (const float*)d_in[3];
  const float* w_q = (const float*)d_in[4];
  const float* v   = (const float*)d_in[5];
  float* out = (float*)d_out;

  char* ws = (char*)d_ws;
  const size_t encBytes = (size_t)BB * HH * SS;            // 16.8 MB int8
  const size_t gBytes   = (size_t)3 * BB * SS * QQ * 2;    // 70.8 MB fp16
  const size_t wqBytes  = (size_t)HH * 96 * 4;             // 196 KB int8-packed
  const size_t gumBytes = (size_t)BB * SS * SS * 4;        // 33.6 MB fp32
  int8_t*   enc8 = (int8_t*)ws;
  __half*   G    = (__half*)(ws + encBytes);
  uint32_t* wq8d = (uint32_t*)(ws + encBytes + gBytes);
  float*    gumP = (float*)(ws + encBytes + gBytes + wqBytes);
  size_t goff = (encBytes + gBytes + wqBytes + gumBytes + 1023) & ~(size_t)1023;
  double* lpb = (double*)(ws + goff);
  double* entb = lpb + BB;

  dim3 gA1(8, BB);
  k_enc<<<gA1, 256, 0, stream>>>(inputs, Wc, bc, enc8);
  dim3 gA2(6, BB, 3);
  k_G<<<gA2, 256, 0, stream>>>(inputs, Wq, G);
  k_wq8<<<HH, 96, 0, stream>>>(w_q, wq8d);
  k_gum<<<(BB * SS * SS) / 1024, 1024, 0, stream>>>(gumP);
  k_scan<<<BB, 1024, 0, stream>>>(wq8d, v, enc8, G, gumP, out, lpb, entb);
  k_final<<<1, 64, 0, stream>>>(lpb, entb, out);
}